// Round 10
// baseline (77.466 us; speedup 1.0000x reference)
//
#include <hip/hip_runtime.h>
#include <math.h>

#define B_ 4
#define T_ 64
#define D_ 8
#define V_ 2000
#define LOG2PI_F 1.8378770664093453f
#define NSEG 8                     /* 8-step publish segments */
#define NSCAN 10                   /* 10 scan blocks x 2 chains = 20 chains */
#define NTAB 4
#define NCONS 1024
#define FLAG_STRIDE 32             /* one flag per 128B line */
#define TDONE_IDX 32               /* after the 32 segment flags */

#define RCP(x) __builtin_amdgcn_rcpf(x)

__device__ __forceinline__ float rdl(float v, int lane) {
  return __int_as_float(__builtin_amdgcn_readlane(__float_as_int(v), lane));
}

// Cholesky of (A + diag(dadd)) with A read from LDS (broadcast, saves VGPRs).
__device__ __forceinline__ float chol_quad_lds(const float* sA, const float dadd[D_],
                                               const float eta[D_], float& logdet) {
  float L[D_][D_];
  float rs[D_];
  float p0 = 1.f, p1 = 1.f;
#pragma unroll
  for (int j = 0; j < D_; ++j) {
    float c = sA[j * 8 + j] + dadd[j];
#pragma unroll
    for (int k = 0; k < D_; ++k) {
      if (k < j) c -= L[j][k] * L[j][k];
    }
    if (j < 4) p0 *= c; else p1 *= c;
    float r = rsqrtf(c);
    rs[j] = r;
#pragma unroll
    for (int i = 0; i < D_; ++i) {
      if (i > j) {
        float s = sA[i * 8 + j];
#pragma unroll
        for (int k = 0; k < D_; ++k) {
          if (k < j) s -= L[i][k] * L[j][k];
        }
        L[i][j] = s * r;
      }
    }
  }
  logdet = __logf(p0) + __logf(p1);
  float z[D_];
  float q = 0.f;
#pragma unroll
  for (int i = 0; i < D_; ++i) {
    float s = eta[i];
#pragma unroll
    for (int k = 0; k < D_; ++k) {
      if (k < i) s -= L[i][k] * z[k];
    }
    z[i] = s * rs[i];
    q = fmaf(z[i], z[i], q);
  }
  return q;
}

// Chain c = b*5 + r (b=0..3):
//   r==0   : exact chain, ts=0, publishes t=0..31  (segments 0..3)
//   r==1..4: spec chain s=r+3, ts=8r, 24-step warmup, publishes t in [8s,8s+8)
// blocks 0..9    : scan, TWO interleaved chains per wave (2*bid, 2*bid+1)
// blocks 10..13  : decoder table + TDONE counter
// blocks 14..1037: consumers; relaxed-load polls + s_sleep
extern "C" __global__ void __launch_bounds__(256)
k_fused(const int* __restrict__ sent, const float* __restrict__ em_mu,
        const float* __restrict__ em_cho, const float* __restrict__ tr_mu,
        const float* __restrict__ tr_cho, const float* __restrict__ dec_mu,
        const float* __restrict__ dec_cho, float* __restrict__ lam0_ws,
        float* __restrict__ eta0_ws, float* __restrict__ table,
        int* __restrict__ flags, float* __restrict__ out) {
  const int bid = blockIdx.x;
  const int tid = threadIdx.x;

  if (bid < NSCAN) {
    // ================= scan block: 2 chains =================
    __shared__ float sC[16][16], sCi[16][16], sLt[16][16];
    __shared__ float sEt[16], sMu[16];
    __shared__ float sLamW[2][32][8], sWmuT[2][32][8];

    const int c0 = bid * 2, c1 = bid * 2 + 1;
    const int cb[2] = {c0 / 5, c1 / 5};
    const int cr[2] = {c0 % 5, c1 % 5};
    const int cts[2] = {cr[0] == 0 ? 0 : 8 * cr[0], cr[1] == 0 ? 0 : 8 * cr[1]};
    const int cpf[2] = {cr[0] == 0 ? 0 : 24, cr[1] == 0 ? 0 : 24};

    if (tid < 64) {
      const int which = tid >> 5, k = tid & 31;
      const int swd = sent[cb[which] * T_ + cts[which] + k];
      const float4* pc = (const float4*)(em_cho + swd * D_);
      const float4* pm = (const float4*)(em_mu + swd * D_);
      float4 cc0 = pc[0], cc1 = pc[1];
      float4 m0 = pm[0], m1 = pm[1];
      sLamW[which][k][0] = RCP(cc0.x * cc0.x);
      sLamW[which][k][1] = RCP(cc0.y * cc0.y);
      sLamW[which][k][2] = RCP(cc0.z * cc0.z);
      sLamW[which][k][3] = RCP(cc0.w * cc0.w);
      sLamW[which][k][4] = RCP(cc1.x * cc1.x);
      sLamW[which][k][5] = RCP(cc1.y * cc1.y);
      sLamW[which][k][6] = RCP(cc1.z * cc1.z);
      sLamW[which][k][7] = RCP(cc1.w * cc1.w);
      sWmuT[which][k][0] = m0.x; sWmuT[which][k][1] = m0.y;
      sWmuT[which][k][2] = m0.z; sWmuT[which][k][3] = m0.w;
      sWmuT[which][k][4] = m1.x; sWmuT[which][k][5] = m1.y;
      sWmuT[which][k][6] = m1.z; sWmuT[which][k][7] = m1.w;
    }

    // preamble: lam_t = inv(C^T C), eta_t = lam_t @ mu
    sC[tid >> 4][tid & 15] = tr_cho[tid];
    if (tid < 16) sMu[tid] = tr_mu[tid];
    __syncthreads();
    if (tid < 16) {
      const int j = tid;
      float col[16];
#pragma unroll
      for (int i = 0; i < 16; ++i) {
        float v = (i == j) ? 1.f : 0.f;
#pragma unroll
        for (int k = 0; k < 16; ++k) {
          if (k < i) v = fmaf(-sC[i][k], col[k], v);
        }
        col[i] = v * RCP(sC[i][i]);
      }
#pragma unroll
      for (int i = 0; i < 16; ++i) sCi[i][j] = col[i];
    }
    __syncthreads();
    {
      int i = tid >> 4, jq = tid & 15;
      float v = 0.f;
#pragma unroll
      for (int k = 0; k < 16; ++k) v = fmaf(sCi[i][k], sCi[jq][k], v);
      sLt[i][jq] = v;
    }
    __syncthreads();
    if (tid < 16) {
      float v = 0.f;
#pragma unroll
      for (int k = 0; k < 16; ++k) v = fmaf(sLt[tid][k], sMu[k], v);
      sEt[tid] = v;
    }
    __syncthreads();
    if (tid >= 64) return;  // wave 0 only from here

    const int i = tid & 7;
    float ltAA[8], ltAB[8], ltBA[8], ltBB[8];
#pragma unroll
    for (int j = 0; j < 8; ++j) {
      ltAA[j] = sLt[i][j];
      ltAB[j] = sLt[i][8 + j];
      ltBA[j] = sLt[8 + i][j];
      ltBB[j] = sLt[8 + i][8 + j];
    }
    const float etH = sEt[i], etT = sEt[8 + i];

    float lam[2][8], eta[2], lamw[2], wmu[2];
#pragma unroll
    for (int c = 0; c < 2; ++c) {
#pragma unroll
      for (int j = 0; j < 8; ++j) lam[c][j] = (j == i) ? 1.f : 0.f;
      eta[c] = 0.f;
      lamw[c] = sLamW[c][0][i];
      wmu[c] = sWmuT[c][0][i];
    }

#pragma unroll 1
    for (int tl = 0; tl < 32; ++tl) {
      float lamw_n[2], wmu_n[2];
#pragma unroll
      for (int c = 0; c < 2; ++c) {
        lamw_n[c] = sLamW[c][(tl + 1) & 31][i];
        wmu_n[c] = sWmuT[c][(tl + 1) & 31][i];
      }

      float A[2][8], Bm[2][8], Cr[2][8], Dm[2][8], ev[2], et[2];
#pragma unroll
      for (int c = 0; c < 2; ++c) {
#pragma unroll
        for (int j = 0; j < 8; ++j) {
          A[c][j] = ltAA[j] + lam[c][j];
          Bm[c][j] = ltAB[j];
          Cr[c][j] = ltBA[j];
          Dm[c][j] = ltBB[j];
        }
        ev[c] = etH + eta[c];
        et[c] = etT;
      }

      // 2x2-block forward elimination, both chains interleaved
#pragma unroll
      for (int kk = 0; kk < 8; kk += 2) {
        const int k1 = kk, k2 = kk + 1;
        float sA1[2][8], sA2[2][8], sB1[2][8], sB2[2][8], sE1[2], sE2[2];
#pragma unroll
        for (int c = 0; c < 2; ++c) {
#pragma unroll
          for (int j = 0; j < 8; ++j) {
            if (j >= k1) {
              sA1[c][j] = rdl(A[c][j], k1);
              sA2[c][j] = rdl(A[c][j], k2);
            }
          }
#pragma unroll
          for (int j = 0; j < 8; ++j) {
            sB1[c][j] = rdl(Bm[c][j], k1);
            sB2[c][j] = rdl(Bm[c][j], k2);
          }
          sE1[c] = rdl(ev[c], k1);
          sE2[c] = rdl(ev[c], k2);
        }
#pragma unroll
        for (int c = 0; c < 2; ++c) {
          float p11 = sA1[c][k1], p12 = sA1[c][k2];
          float p21 = sA2[c][k1], p22 = sA2[c][k2];
          float rdet = RCP(fmaf(p11, p22, -(p12 * p21)));
          float a1 = A[c][k1], a2 = A[c][k2];
          float g1 = (i > k2) ? (a1 * p22 - a2 * p21) * rdet : 0.f;
          float g2 = (i > k2) ? (a2 * p11 - a1 * p12) * rdet : 0.f;
          float c1 = Cr[c][k1], c2 = Cr[c][k2];
          float h1 = (c1 * p22 - c2 * p21) * rdet;
          float h2 = (c2 * p11 - c1 * p12) * rdet;
#pragma unroll
          for (int j = 0; j < 8; ++j) {
            if (j >= kk + 2) {
              A[c][j] = fmaf(-g1, sA1[c][j], fmaf(-g2, sA2[c][j], A[c][j]));
              Cr[c][j] = fmaf(-h1, sA1[c][j], fmaf(-h2, sA2[c][j], Cr[c][j]));
            }
          }
#pragma unroll
          for (int j = 0; j < 8; ++j) {
            Bm[c][j] = fmaf(-g1, sB1[c][j], fmaf(-g2, sB2[c][j], Bm[c][j]));
            Dm[c][j] = fmaf(-h1, sB1[c][j], fmaf(-h2, sB2[c][j], Dm[c][j]));
          }
          ev[c] = fmaf(-g1, sE1[c], fmaf(-g2, sE2[c], ev[c]));
          et[c] = fmaf(-h1, sE1[c], fmaf(-h2, sE2[c], et[c]));
        }
      }

      // epilogue + publish
#pragma unroll
      for (int c = 0; c < 2; ++c) {
#pragma unroll
        for (int j = 0; j < 8; ++j) lam[c][j] = (j == i) ? Dm[c][j] + lamw[c] : Dm[c][j];
        eta[c] = fmaf(lamw[c], wmu[c], et[c]);
      }

      bool due0 = (tl >= cpf[0]), due1 = (tl >= cpf[1]);
      if (due0 && tid < 8) {
        const int t = cts[0] + tl;
        float4* dst = (float4*)(lam0_ws + (cb[0] * T_ + t) * 64 + i * 8);
        dst[0] = make_float4(lam[0][0], lam[0][1], lam[0][2], lam[0][3]);
        dst[1] = make_float4(lam[0][4], lam[0][5], lam[0][6], lam[0][7]);
        eta0_ws[(cb[0] * T_ + t) * 8 + i] = eta[0];
      }
      if (due1 && tid < 8) {
        const int t = cts[1] + tl;
        float4* dst = (float4*)(lam0_ws + (cb[1] * T_ + t) * 64 + i * 8);
        dst[0] = make_float4(lam[1][0], lam[1][1], lam[1][2], lam[1][3]);
        dst[1] = make_float4(lam[1][4], lam[1][5], lam[1][6], lam[1][7]);
        eta0_ws[(cb[1] * T_ + t) * 8 + i] = eta[1];
      }
      const bool f0 = due0 && ((tl & 7) == 7);
      const bool f1 = due1 && ((tl & 7) == 7);
      if (f0 || f1) {
        __threadfence();  // release
        if (tid == 0) {
          if (f0)
            __hip_atomic_store(&flags[(cb[0] * NSEG + ((cts[0] + tl) >> 3)) * FLAG_STRIDE],
                               1, __ATOMIC_RELAXED, __HIP_MEMORY_SCOPE_AGENT);
          if (f1)
            __hip_atomic_store(&flags[(cb[1] * NSEG + ((cts[1] + tl) >> 3)) * FLAG_STRIDE],
                               1, __ATOMIC_RELAXED, __HIP_MEMORY_SCOPE_AGENT);
        }
      }
#pragma unroll
      for (int c = 0; c < 2; ++c) {
        lamw[c] = lamw_n[c];
        wmu[c] = wmu_n[c];
      }
    }
    return;
  }

  if (bid < NSCAN + NTAB) {
    // ================= table block =================
    const int v0 = (bid - NSCAN) * 500;
#pragma unroll
    for (int it = 0; it < 2; ++it) {
      int off = it * 256 + tid;
      if (off < 500) {
        int v = v0 + off;
        float sl = 0.f, q = 0.f;
#pragma unroll
        for (int j = 0; j < D_; ++j) {
          float c = dec_cho[v * D_ + j];
          float m = dec_mu[v * D_ + j];
          float l = 1.f / (c * c);
          float e = m * l;
          sl += __logf(l);
          q = fmaf(e, m, q);
          table[j * V_ + v] = l;
          table[(D_ + j) * V_ + v] = e;
        }
        table[16 * V_ + v] = -0.5f * (8.f * LOG2PI_F - sl + q);
      }
    }
    __threadfence();
    __syncthreads();
    if (tid == 0) atomicAdd(&flags[TDONE_IDX * FLAG_STRIDE], 1);
    return;
  }

  // ================= consumer block =================
  {
    const int cid = bid - NSCAN - NTAB;    // 0..1023
    const int bt = cid >> 2;               // 0..255  (= b*64 + t)
    const int quarter = cid & 3;
    const int fi = (bt >> 6) * NSEG + ((bt & 63) >> 3);

    if (tid == 0) {
      const int* fch = &flags[fi * FLAG_STRIDE];
      while (__hip_atomic_load(fch, __ATOMIC_RELAXED, __HIP_MEMORY_SCOPE_AGENT) == 0)
        __builtin_amdgcn_s_sleep(7);
      const int* ftd = &flags[TDONE_IDX * FLAG_STRIDE];
      while (__hip_atomic_load(ftd, __ATOMIC_RELAXED, __HIP_MEMORY_SCOPE_AGENT) < 4)
        __builtin_amdgcn_s_sleep(7);
      __threadfence();  // acquire
    }
    __syncthreads();

    __shared__ float sL[64];
    __shared__ float sE[8];
    if (tid < 64) sL[tid] = lam0_ws[bt * 64 + tid];
    if (tid < 8) sE[tid] = eta0_ws[bt * 8 + tid];
    __syncthreads();

    float e0[D_];
#pragma unroll
    for (int ii = 0; ii < D_; ++ii) e0[ii] = sE[ii];
    float zero[D_];
#pragma unroll
    for (int j = 0; j < D_; ++j) zero[j] = 0.f;
    float ld0;
    float q0 = chol_quad_lds(sL, zero, e0, ld0);
    const float zeta0 = -0.5f * (8.f * LOG2PI_F - ld0 + q0);

#pragma unroll 1
    for (int it = 0; it < 2; ++it) {
      int off = it * 256 + tid;
      if (off < 500) {
        int v = quarter * 500 + off;
        float dl[D_], ef[D_];
#pragma unroll
        for (int j = 0; j < D_; ++j) {
          dl[j] = table[j * V_ + v];
          ef[j] = e0[j] + table[(D_ + j) * V_ + v];
        }
        float z1 = table[16 * V_ + v];
        float ldn;
        float qn = chol_quad_lds(sL, dl, ef, ldn);
        float zeta_n = -0.5f * (8.f * LOG2PI_F - ldn + qn);
        out[bt * V_ + v] = zeta0 + z1 - zeta_n;
      }
    }
  }
}

extern "C" void kernel_launch(void* const* d_in, const int* in_sizes, int n_in,
                              void* d_out, int out_size, void* d_ws, size_t ws_size,
                              hipStream_t stream) {
  const int* sent = (const int*)d_in[0];
  const float* em_mu = (const float*)d_in[2];
  const float* em_cho = (const float*)d_in[3];
  const float* tr_mu = (const float*)d_in[4];
  const float* tr_cho = (const float*)d_in[5];
  const float* dec_mu = (const float*)d_in[6];
  const float* dec_cho = (const float*)d_in[7];
  float* out = (float*)d_out;

  float* ws = (float*)d_ws;
  float* lam0_ws = ws;                        // 16384 floats
  float* eta0_ws = ws + 16384;                // 2048 floats
  float* table = ws + 16384 + 2048;           // 34000 floats
  int* flags = (int*)(ws + 16384 + 2048 + 34000);  // (32+1)*32 ints, line-padded

  hipMemsetAsync(flags, 0, (TDONE_IDX + 1) * FLAG_STRIDE * sizeof(int), stream);
  k_fused<<<dim3(NSCAN + NTAB + NCONS), dim3(256), 0, stream>>>(
      sent, em_mu, em_cho, tr_mu, tr_cho, dec_mu, dec_cho,
      lam0_ws, eta0_ws, table, flags, out);
}

// Round 11
// 52.250 us; speedup vs baseline: 1.4826x; 1.4826x over previous
//
#include <hip/hip_runtime.h>
#include <math.h>

#define B_ 4
#define T_ 64
#define D_ 8
#define V_ 2000
#define LOG2PI_F 1.8378770664093453f
#define SEG 8                      /* steps per published segment */
#define NSEG (T_ / SEG)            /* 8 segments per batch */
#define WARM 16                    /* speculative warmup steps */
#define FLAG_STRIDE 32             /* one flag per 128B line */
#define TDONE_IDX (B_ * NSEG)      /* flags[32*32] = table-done counter */
#define NSCAN (B_ * NSEG)          /* 32 scan blocks */
#define NTAB 4
#define NCONS 1024

#define RCP(x) __builtin_amdgcn_rcpf(x)

__device__ __forceinline__ float rdl(float v, int lane) {
  return __int_as_float(__builtin_amdgcn_readlane(__float_as_int(v), lane));
}
// broadcast from lane k via the DS pipe (uniform bpermute address)
__device__ __forceinline__ float bpc(float v, int lane) {
  return __int_as_float(__builtin_amdgcn_ds_bpermute(lane * 4, __float_as_int(v)));
}

// Cholesky of (A + diag(dadd)) with A read from LDS (broadcast, saves VGPRs).
__device__ __forceinline__ float chol_quad_lds(const float* sA, const float dadd[D_],
                                               const float eta[D_], float& logdet) {
  float L[D_][D_];
  float rs[D_];
  float p0 = 1.f, p1 = 1.f;
#pragma unroll
  for (int j = 0; j < D_; ++j) {
    float c = sA[j * 8 + j] + dadd[j];
#pragma unroll
    for (int k = 0; k < D_; ++k) {
      if (k < j) c -= L[j][k] * L[j][k];
    }
    if (j < 4) p0 *= c; else p1 *= c;
    float r = rsqrtf(c);
    rs[j] = r;
#pragma unroll
    for (int i = 0; i < D_; ++i) {
      if (i > j) {
        float s = sA[i * 8 + j];
#pragma unroll
        for (int k = 0; k < D_; ++k) {
          if (k < j) s -= L[i][k] * L[j][k];
        }
        L[i][j] = s * r;
      }
    }
  }
  logdet = __logf(p0) + __logf(p1);
  float z[D_];
  float q = 0.f;
#pragma unroll
  for (int i = 0; i < D_; ++i) {
    float s = eta[i];
#pragma unroll
    for (int k = 0; k < D_; ++k) {
      if (k < i) s -= L[i][k] * z[k];
    }
    z[i] = s * rs[i];
    q = fmaf(z[i], z[i], q);
  }
  return q;
}

// blocks 0..31   : scan segments (b = bid>>3, s = bid&7), ONE chain per block.
//                  s<=2 exact (8/16/24 steps); s>=3 warm up WARM=16 steps.
//                  Broadcasts split: k1-row via readlane (VALU pipe),
//                  k2-row via ds_bpermute (DS pipe) -> two issue pipes overlap.
// blocks 32..35  : decoder table + TDONE counter
// blocks 36..1059: consumers (500 cells each); relaxed-load polls + s_sleep
extern "C" __global__ void __launch_bounds__(256)
k_fused(const int* __restrict__ sent, const float* __restrict__ em_mu,
        const float* __restrict__ em_cho, const float* __restrict__ tr_mu,
        const float* __restrict__ tr_cho, const float* __restrict__ dec_mu,
        const float* __restrict__ dec_cho, float* __restrict__ lam0_ws,
        float* __restrict__ eta0_ws, float* __restrict__ table,
        int* __restrict__ flags, float* __restrict__ out) {
  const int bid = blockIdx.x;
  const int tid = threadIdx.x;

  if (bid < NSCAN) {
    // ================= scan segment block =================
    __shared__ float sC[16][16], sCi[16][16], sLt[16][16];
    __shared__ float sEt[16], sMu[16];
    __shared__ float sLamW[32][8], sWmuT[32][8];
    const int b = bid >> 3;
    const int s = bid & (NSEG - 1);
    const int t_end = s * SEG + SEG;
    const int t_start = (s * SEG > WARM) ? (s * SEG - WARM) : 0;
    const int nsteps = t_end - t_start;   // 8,16,24,24,...,24

    if (tid < nsteps) {
      const int swd = sent[b * T_ + t_start + tid];
      const float4* pc = (const float4*)(em_cho + swd * D_);
      const float4* pm = (const float4*)(em_mu + swd * D_);
      float4 c0 = pc[0], c1 = pc[1];
      float4 m0 = pm[0], m1 = pm[1];
      sLamW[tid][0] = RCP(c0.x * c0.x);
      sLamW[tid][1] = RCP(c0.y * c0.y);
      sLamW[tid][2] = RCP(c0.z * c0.z);
      sLamW[tid][3] = RCP(c0.w * c0.w);
      sLamW[tid][4] = RCP(c1.x * c1.x);
      sLamW[tid][5] = RCP(c1.y * c1.y);
      sLamW[tid][6] = RCP(c1.z * c1.z);
      sLamW[tid][7] = RCP(c1.w * c1.w);
      sWmuT[tid][0] = m0.x; sWmuT[tid][1] = m0.y;
      sWmuT[tid][2] = m0.z; sWmuT[tid][3] = m0.w;
      sWmuT[tid][4] = m1.x; sWmuT[tid][5] = m1.y;
      sWmuT[tid][6] = m1.z; sWmuT[tid][7] = m1.w;
    }

    // preamble: lam_t = inv(C^T C), eta_t = lam_t @ mu
    sC[tid >> 4][tid & 15] = tr_cho[tid];
    if (tid < 16) sMu[tid] = tr_mu[tid];
    __syncthreads();
    if (tid < 16) {
      const int j = tid;
      float col[16];
#pragma unroll
      for (int i = 0; i < 16; ++i) {
        float v = (i == j) ? 1.f : 0.f;
#pragma unroll
        for (int k = 0; k < 16; ++k) {
          if (k < i) v = fmaf(-sC[i][k], col[k], v);
        }
        col[i] = v * RCP(sC[i][i]);
      }
#pragma unroll
      for (int i = 0; i < 16; ++i) sCi[i][j] = col[i];
    }
    __syncthreads();
    {
      int i = tid >> 4, jq = tid & 15;
      float v = 0.f;
#pragma unroll
      for (int k = 0; k < 16; ++k) v = fmaf(sCi[i][k], sCi[jq][k], v);
      sLt[i][jq] = v;
    }
    __syncthreads();
    if (tid < 16) {
      float v = 0.f;
#pragma unroll
      for (int k = 0; k < 16; ++k) v = fmaf(sLt[tid][k], sMu[k], v);
      sEt[tid] = v;
    }
    __syncthreads();
    if (tid >= 64) return;  // wave 0 only from here; no more barriers

    const int i = tid & 7;
    float ltAA[8], ltAB[8], ltBA[8], ltBB[8];
#pragma unroll
    for (int j = 0; j < 8; ++j) {
      ltAA[j] = sLt[i][j];
      ltAB[j] = sLt[i][8 + j];
      ltBA[j] = sLt[8 + i][j];
      ltBB[j] = sLt[8 + i][8 + j];
    }
    const float etH = sEt[i], etT = sEt[8 + i];

    float lam[8];
#pragma unroll
    for (int j = 0; j < 8; ++j) lam[j] = (j == i) ? 1.f : 0.f;
    float eta = 0.f;

    float* lamOut = lam0_ws + b * T_ * 64;
    float* etaOut = eta0_ws + b * T_ * 8;

    float lamw = sLamW[0][i];
    float wmu = sWmuT[0][i];

#pragma unroll 1
    for (int tl = 0; tl < nsteps; ++tl) {
      float lamw_n = sLamW[(tl + 1) & 31][i];
      float wmu_n = sWmuT[(tl + 1) & 31][i];

      float A[8], Bm[8], Cr[8], Dm[8];
#pragma unroll
      for (int j = 0; j < 8; ++j) {
        A[j] = ltAA[j] + lam[j];
        Bm[j] = ltAB[j];
        Cr[j] = ltBA[j];
        Dm[j] = ltBB[j];
      }
      float ev = etH + eta;
      float et = etT;

      // 2x2-block forward elimination: 4 rounds, Schur lands in Dm/et.
      // k1-row broadcasts on the VALU pipe (readlane), k2-row on the DS pipe
      // (ds_bpermute) -> the two broadcast streams issue concurrently.
#pragma unroll
      for (int kk = 0; kk < 8; kk += 2) {
        const int k1 = kk, k2 = kk + 1;
        float sA1[8], sA2[8], sB1[8], sB2[8];
#pragma unroll
        for (int j = 0; j < 8; ++j) {
          if (j >= k1) {
            sA1[j] = rdl(A[j], k1);
            sA2[j] = bpc(A[j], k2);
          }
        }
#pragma unroll
        for (int j = 0; j < 8; ++j) {
          sB1[j] = rdl(Bm[j], k1);
          sB2[j] = bpc(Bm[j], k2);
        }
        float sE1 = rdl(ev, k1), sE2 = bpc(ev, k2);
        float p11 = sA1[k1], p12 = sA1[k2];
        float p21 = sA2[k1], p22 = sA2[k2];
        float rdet = RCP(fmaf(p11, p22, -(p12 * p21)));
        float a1 = A[k1], a2 = A[k2];
        float g1 = (i > k2) ? (a1 * p22 - a2 * p21) * rdet : 0.f;
        float g2 = (i > k2) ? (a2 * p11 - a1 * p12) * rdet : 0.f;
        float c1 = Cr[k1], c2 = Cr[k2];
        float h1 = (c1 * p22 - c2 * p21) * rdet;
        float h2 = (c2 * p11 - c1 * p12) * rdet;
#pragma unroll
        for (int j = 0; j < 8; ++j) {
          if (j >= kk + 2) {
            A[j] = fmaf(-g1, sA1[j], fmaf(-g2, sA2[j], A[j]));
            Cr[j] = fmaf(-h1, sA1[j], fmaf(-h2, sA2[j], Cr[j]));
          }
        }
#pragma unroll
        for (int j = 0; j < 8; ++j) {
          Bm[j] = fmaf(-g1, sB1[j], fmaf(-g2, sB2[j], Bm[j]));
          Dm[j] = fmaf(-h1, sB1[j], fmaf(-h2, sB2[j], Dm[j]));
        }
        ev = fmaf(-g1, sE1, fmaf(-g2, sE2, ev));
        et = fmaf(-h1, sE1, fmaf(-h2, sE2, et));
      }

      // epilogue: lam2 = Schur + diag(lamw); eta2 = et + lamw*wmu
#pragma unroll
      for (int j = 0; j < 8; ++j) lam[j] = (j == i) ? Dm[j] + lamw : Dm[j];
      eta = fmaf(lamw, wmu, et);

      const int t = t_start + tl;
      if (t >= s * SEG && tid < 8) {
        float4* dst = (float4*)(lamOut + t * 64 + i * 8);
        dst[0] = make_float4(lam[0], lam[1], lam[2], lam[3]);
        dst[1] = make_float4(lam[4], lam[5], lam[6], lam[7]);
        etaOut[t * 8 + i] = eta;
      }
      if (tl == nsteps - 1) {
        __threadfence();  // release
        if (tid == 0)
          __hip_atomic_store(&flags[(b * NSEG + s) * FLAG_STRIDE], 1,
                             __ATOMIC_RELAXED, __HIP_MEMORY_SCOPE_AGENT);
      }
      lamw = lamw_n;
      wmu = wmu_n;
    }
    return;
  }

  if (bid < NSCAN + NTAB) {
    // ================= table block =================
    const int v0 = (bid - NSCAN) * 500;
#pragma unroll
    for (int it = 0; it < 2; ++it) {
      int off = it * 256 + tid;
      if (off < 500) {
        int v = v0 + off;
        float sl = 0.f, q = 0.f;
#pragma unroll
        for (int j = 0; j < D_; ++j) {
          float c = dec_cho[v * D_ + j];
          float m = dec_mu[v * D_ + j];
          float l = 1.f / (c * c);
          float e = m * l;
          sl += __logf(l);
          q = fmaf(e, m, q);
          table[j * V_ + v] = l;
          table[(D_ + j) * V_ + v] = e;
        }
        table[16 * V_ + v] = -0.5f * (8.f * LOG2PI_F - sl + q);
      }
    }
    __threadfence();
    __syncthreads();
    if (tid == 0) atomicAdd(&flags[TDONE_IDX * FLAG_STRIDE], 1);
    return;
  }

  // ================= consumer block =================
  {
    const int cid = bid - NSCAN - NTAB;    // 0..1023
    const int bt = cid >> 2;               // 0..255  (= b*64 + t)
    const int quarter = cid & 3;
    const int fi = (bt >> 6) * NSEG + ((bt & 63) >> 3);

    if (tid == 0) {
      const int* fch = &flags[fi * FLAG_STRIDE];
      while (__hip_atomic_load(fch, __ATOMIC_RELAXED, __HIP_MEMORY_SCOPE_AGENT) == 0)
        __builtin_amdgcn_s_sleep(7);
      const int* ftd = &flags[TDONE_IDX * FLAG_STRIDE];
      while (__hip_atomic_load(ftd, __ATOMIC_RELAXED, __HIP_MEMORY_SCOPE_AGENT) < 4)
        __builtin_amdgcn_s_sleep(7);
      __threadfence();  // acquire
    }
    __syncthreads();

    __shared__ float sL[64];
    __shared__ float sE[8];
    if (tid < 64) sL[tid] = lam0_ws[bt * 64 + tid];
    if (tid < 8) sE[tid] = eta0_ws[bt * 8 + tid];
    __syncthreads();

    float e0[D_];
#pragma unroll
    for (int ii = 0; ii < D_; ++ii) e0[ii] = sE[ii];
    float zero[D_];
#pragma unroll
    for (int j = 0; j < D_; ++j) zero[j] = 0.f;
    float ld0;
    float q0 = chol_quad_lds(sL, zero, e0, ld0);
    const float zeta0 = -0.5f * (8.f * LOG2PI_F - ld0 + q0);

#pragma unroll 1
    for (int it = 0; it < 2; ++it) {
      int off = it * 256 + tid;
      if (off < 500) {
        int v = quarter * 500 + off;
        float dl[D_], ef[D_];
#pragma unroll
        for (int j = 0; j < D_; ++j) {
          dl[j] = table[j * V_ + v];
          ef[j] = e0[j] + table[(D_ + j) * V_ + v];
        }
        float z1 = table[16 * V_ + v];
        float ldn;
        float qn = chol_quad_lds(sL, dl, ef, ldn);
        float zeta_n = -0.5f * (8.f * LOG2PI_F - ldn + qn);
        out[bt * V_ + v] = zeta0 + z1 - zeta_n;
      }
    }
  }
}

extern "C" void kernel_launch(void* const* d_in, const int* in_sizes, int n_in,
                              void* d_out, int out_size, void* d_ws, size_t ws_size,
                              hipStream_t stream) {
  const int* sent = (const int*)d_in[0];
  const float* em_mu = (const float*)d_in[2];
  const float* em_cho = (const float*)d_in[3];
  const float* tr_mu = (const float*)d_in[4];
  const float* tr_cho = (const float*)d_in[5];
  const float* dec_mu = (const float*)d_in[6];
  const float* dec_cho = (const float*)d_in[7];
  float* out = (float*)d_out;

  float* ws = (float*)d_ws;
  float* lam0_ws = ws;                        // 16384 floats
  float* eta0_ws = ws + 16384;                // 2048 floats
  float* table = ws + 16384 + 2048;           // 34000 floats
  int* flags = (int*)(ws + 16384 + 2048 + 34000);  // (32+1)*32 ints, line-padded

  hipMemsetAsync(flags, 0, (TDONE_IDX + 1) * FLAG_STRIDE * sizeof(int), stream);
  k_fused<<<dim3(NSCAN + NTAB + NCONS), dim3(256), 0, stream>>>(
      sent, em_mu, em_cho, tr_mu, tr_cho, dec_mu, dec_cho,
      lam0_ws, eta0_ws, table, flags, out);
}

// Round 12
// 30.800 us; speedup vs baseline: 2.5152x; 1.6964x over previous
//
#include <hip/hip_runtime.h>
#include <math.h>

#define B_ 4
#define T_ 64
#define D_ 8
#define V_ 2000
#define LOG2PI_F 1.8378770664093453f
#define SEG 8
#define NSEG (T_ / SEG)            /* 8 segments per batch */
#define WARM 8                     /* speculative warmup steps */
#define NSCAN (B_ * NSEG)          /* 32 scan blocks */

#define RCP(x) __builtin_amdgcn_rcpf(x)

__device__ __forceinline__ float rdl(float v, int lane) {
  return __int_as_float(__builtin_amdgcn_readlane(__float_as_int(v), lane));
}
// broadcast from lane k via the DS pipe (uniform bpermute address)
__device__ __forceinline__ float bpc(float v, int lane) {
  return __int_as_float(__builtin_amdgcn_ds_bpermute(lane * 4, __float_as_int(v)));
}

// Cholesky of (A + diag(dadd)) with A read from LDS (broadcast reads).
__device__ __forceinline__ float chol_quad_lds(const float* sA, const float dadd[D_],
                                               const float eta[D_], float& logdet) {
  float L[D_][D_];
  float rs[D_];
  float p0 = 1.f, p1 = 1.f;
#pragma unroll
  for (int j = 0; j < D_; ++j) {
    float c = sA[j * 8 + j] + dadd[j];
#pragma unroll
    for (int k = 0; k < D_; ++k) {
      if (k < j) c -= L[j][k] * L[j][k];
    }
    if (j < 4) p0 *= c; else p1 *= c;
    float r = rsqrtf(c);
    rs[j] = r;
#pragma unroll
    for (int i = 0; i < D_; ++i) {
      if (i > j) {
        float s = sA[i * 8 + j];
#pragma unroll
        for (int k = 0; k < D_; ++k) {
          if (k < j) s -= L[i][k] * L[j][k];
        }
        L[i][j] = s * r;
      }
    }
  }
  logdet = __logf(p0) + __logf(p1);
  float z[D_];
  float q = 0.f;
#pragma unroll
  for (int i = 0; i < D_; ++i) {
    float s = eta[i];
#pragma unroll
    for (int k = 0; k < D_; ++k) {
      if (k < i) s -= L[i][k] * z[k];
    }
    z[i] = s * rs[i];
    q = fmaf(z[i], z[i], q);
  }
  return q;
}

// Kernel 1: 32 scan blocks (b = bid>>3, s = bid&7), one chain per block,
// alone on the machine (no consumer contention). s==0: 8 exact steps;
// s>=1: 8-step warmup from neutral init + 8 published steps.
extern "C" __global__ void __launch_bounds__(256)
k_scan(const int* __restrict__ sent, const float* __restrict__ em_mu,
       const float* __restrict__ em_cho, const float* __restrict__ tr_mu,
       const float* __restrict__ tr_cho, float* __restrict__ lam0_ws,
       float* __restrict__ eta0_ws) {
  const int bid = blockIdx.x;
  const int tid = threadIdx.x;

  __shared__ float sC[16][16], sCi[16][16], sLt[16][16];
  __shared__ float sEt[16], sMu[16];
  __shared__ float sLamW[16][8], sWmuT[16][8];
  const int b = bid >> 3;
  const int s = bid & (NSEG - 1);
  const int t_start = (s >= 1) ? (s * SEG - WARM) : 0;
  const int nsteps = s * SEG + SEG - t_start;   // 8 or 16

  if (tid < nsteps) {
    const int swd = sent[b * T_ + t_start + tid];
    const float4* pc = (const float4*)(em_cho + swd * D_);
    const float4* pm = (const float4*)(em_mu + swd * D_);
    float4 c0 = pc[0], c1 = pc[1];
    float4 m0 = pm[0], m1 = pm[1];
    sLamW[tid][0] = RCP(c0.x * c0.x);
    sLamW[tid][1] = RCP(c0.y * c0.y);
    sLamW[tid][2] = RCP(c0.z * c0.z);
    sLamW[tid][3] = RCP(c0.w * c0.w);
    sLamW[tid][4] = RCP(c1.x * c1.x);
    sLamW[tid][5] = RCP(c1.y * c1.y);
    sLamW[tid][6] = RCP(c1.z * c1.z);
    sLamW[tid][7] = RCP(c1.w * c1.w);
    sWmuT[tid][0] = m0.x; sWmuT[tid][1] = m0.y;
    sWmuT[tid][2] = m0.z; sWmuT[tid][3] = m0.w;
    sWmuT[tid][4] = m1.x; sWmuT[tid][5] = m1.y;
    sWmuT[tid][6] = m1.z; sWmuT[tid][7] = m1.w;
  }

  // preamble: lam_t = inv(C^T C), eta_t = lam_t @ mu
  sC[tid >> 4][tid & 15] = tr_cho[tid];
  if (tid < 16) sMu[tid] = tr_mu[tid];
  __syncthreads();
  if (tid < 16) {
    const int j = tid;
    float col[16];
#pragma unroll
    for (int i = 0; i < 16; ++i) {
      float v = (i == j) ? 1.f : 0.f;
#pragma unroll
      for (int k = 0; k < 16; ++k) {
        if (k < i) v = fmaf(-sC[i][k], col[k], v);
      }
      col[i] = v * RCP(sC[i][i]);
    }
#pragma unroll
    for (int i = 0; i < 16; ++i) sCi[i][j] = col[i];
  }
  __syncthreads();
  {
    int i = tid >> 4, jq = tid & 15;
    float v = 0.f;
#pragma unroll
    for (int k = 0; k < 16; ++k) v = fmaf(sCi[i][k], sCi[jq][k], v);
    sLt[i][jq] = v;
  }
  __syncthreads();
  if (tid < 16) {
    float v = 0.f;
#pragma unroll
    for (int k = 0; k < 16; ++k) v = fmaf(sLt[tid][k], sMu[k], v);
    sEt[tid] = v;
  }
  __syncthreads();
  if (tid >= 64) return;  // wave 0 only from here; no more barriers

  const int i = tid & 7;
  float ltAA[8], ltAB[8], ltBA[8], ltBB[8];
#pragma unroll
  for (int j = 0; j < 8; ++j) {
    ltAA[j] = sLt[i][j];
    ltAB[j] = sLt[i][8 + j];
    ltBA[j] = sLt[8 + i][j];
    ltBB[j] = sLt[8 + i][8 + j];
  }
  const float etH = sEt[i], etT = sEt[8 + i];

  float lam[8];
#pragma unroll
  for (int j = 0; j < 8; ++j) lam[j] = (j == i) ? 1.f : 0.f;
  float eta = 0.f;

  float* lamOut = lam0_ws + b * T_ * 64;
  float* etaOut = eta0_ws + b * T_ * 8;

  float lamw = sLamW[0][i];
  float wmu = sWmuT[0][i];

#pragma unroll 1
  for (int tl = 0; tl < nsteps; ++tl) {
    float lamw_n = sLamW[(tl + 1) & 15][i];
    float wmu_n = sWmuT[(tl + 1) & 15][i];

    float A[8], Bm[8], Cr[8], Dm[8];
#pragma unroll
    for (int j = 0; j < 8; ++j) {
      A[j] = ltAA[j] + lam[j];
      Bm[j] = ltAB[j];
      Cr[j] = ltBA[j];
      Dm[j] = ltBB[j];
    }
    float ev = etH + eta;
    float et = etT;

    // 2x2-block forward elimination; k1-row via readlane (VALU pipe),
    // k2-row via ds_bpermute (DS pipe).
#pragma unroll
    for (int kk = 0; kk < 8; kk += 2) {
      const int k1 = kk, k2 = kk + 1;
      float sA1[8], sA2[8], sB1[8], sB2[8];
#pragma unroll
      for (int j = 0; j < 8; ++j) {
        if (j >= k1) {
          sA1[j] = rdl(A[j], k1);
          sA2[j] = bpc(A[j], k2);
        }
      }
#pragma unroll
      for (int j = 0; j < 8; ++j) {
        sB1[j] = rdl(Bm[j], k1);
        sB2[j] = bpc(Bm[j], k2);
      }
      float sE1 = rdl(ev, k1), sE2 = bpc(ev, k2);
      float p11 = sA1[k1], p12 = sA1[k2];
      float p21 = sA2[k1], p22 = sA2[k2];
      float rdet = RCP(fmaf(p11, p22, -(p12 * p21)));
      float a1 = A[k1], a2 = A[k2];
      float g1 = (i > k2) ? (a1 * p22 - a2 * p21) * rdet : 0.f;
      float g2 = (i > k2) ? (a2 * p11 - a1 * p12) * rdet : 0.f;
      float c1 = Cr[k1], c2 = Cr[k2];
      float h1 = (c1 * p22 - c2 * p21) * rdet;
      float h2 = (c2 * p11 - c1 * p12) * rdet;
#pragma unroll
      for (int j = 0; j < 8; ++j) {
        if (j >= kk + 2) {
          A[j] = fmaf(-g1, sA1[j], fmaf(-g2, sA2[j], A[j]));
          Cr[j] = fmaf(-h1, sA1[j], fmaf(-h2, sA2[j], Cr[j]));
        }
      }
#pragma unroll
      for (int j = 0; j < 8; ++j) {
        Bm[j] = fmaf(-g1, sB1[j], fmaf(-g2, sB2[j], Bm[j]));
        Dm[j] = fmaf(-h1, sB1[j], fmaf(-h2, sB2[j], Dm[j]));
      }
      ev = fmaf(-g1, sE1, fmaf(-g2, sE2, ev));
      et = fmaf(-h1, sE1, fmaf(-h2, sE2, et));
    }

    // epilogue: lam2 = Schur + diag(lamw); eta2 = et + lamw*wmu
#pragma unroll
    for (int j = 0; j < 8; ++j) lam[j] = (j == i) ? Dm[j] + lamw : Dm[j];
    eta = fmaf(lamw, wmu, et);

    const int t = t_start + tl;
    if (t >= s * SEG && tid < 8) {
      float4* dst = (float4*)(lamOut + t * 64 + i * 8);
      dst[0] = make_float4(lam[0], lam[1], lam[2], lam[3]);
      dst[1] = make_float4(lam[4], lam[5], lam[6], lam[7]);
      etaOut[t * 8 + i] = eta;
    }
    lamw = lamw_n;
    wmu = wmu_n;
  }
}

// Kernel 2: 1024 consumer blocks; (bt = bid>>2, quarter = bid&3), 500 cells
// each; decoder terms computed inline per cell (dec tables are L2-hot).
extern "C" __global__ void __launch_bounds__(256)
k_cons(const float* __restrict__ lam0_ws, const float* __restrict__ eta0_ws,
       const float* __restrict__ dec_mu, const float* __restrict__ dec_cho,
       float* __restrict__ out) {
  const int bt = blockIdx.x >> 2;
  const int quarter = blockIdx.x & 3;

  __shared__ float sL[64];
  __shared__ float sE[8];
  if (threadIdx.x < 64) sL[threadIdx.x] = lam0_ws[bt * 64 + threadIdx.x];
  if (threadIdx.x < 8) sE[threadIdx.x] = eta0_ws[bt * 8 + threadIdx.x];
  __syncthreads();

  float e0[D_];
#pragma unroll
  for (int ii = 0; ii < D_; ++ii) e0[ii] = sE[ii];
  float zero[D_];
#pragma unroll
  for (int j = 0; j < D_; ++j) zero[j] = 0.f;
  float ld0;
  float q0 = chol_quad_lds(sL, zero, e0, ld0);
  const float zeta0 = -0.5f * (8.f * LOG2PI_F - ld0 + q0);

#pragma unroll 1
  for (int it = 0; it < 2; ++it) {
    int off = it * 256 + threadIdx.x;
    if (off < 500) {
      int v = quarter * 500 + off;
      const float4* pm = (const float4*)(dec_mu + v * D_);
      const float4* pc = (const float4*)(dec_cho + v * D_);
      float4 m0 = pm[0], m1 = pm[1];
      float4 c0 = pc[0], c1 = pc[1];
      float mv[D_] = {m0.x, m0.y, m0.z, m0.w, m1.x, m1.y, m1.z, m1.w};
      float cv[D_] = {c0.x, c0.y, c0.z, c0.w, c1.x, c1.y, c1.z, c1.w};
      float dl[D_], ef[D_];
      float sl = 0.f, q1 = 0.f;
#pragma unroll
      for (int j = 0; j < D_; ++j) {
        float l = RCP(cv[j] * cv[j]);
        float e = mv[j] * l;
        dl[j] = l;
        ef[j] = e0[j] + e;
        sl += __logf(l);
        q1 = fmaf(e, mv[j], q1);
      }
      const float zeta1 = -0.5f * (8.f * LOG2PI_F - sl + q1);
      float ldn;
      float qn = chol_quad_lds(sL, dl, ef, ldn);
      float zeta_n = -0.5f * (8.f * LOG2PI_F - ldn + qn);
      out[bt * V_ + v] = zeta0 + zeta1 - zeta_n;
    }
  }
}

extern "C" void kernel_launch(void* const* d_in, const int* in_sizes, int n_in,
                              void* d_out, int out_size, void* d_ws, size_t ws_size,
                              hipStream_t stream) {
  const int* sent = (const int*)d_in[0];
  const float* em_mu = (const float*)d_in[2];
  const float* em_cho = (const float*)d_in[3];
  const float* tr_mu = (const float*)d_in[4];
  const float* tr_cho = (const float*)d_in[5];
  const float* dec_mu = (const float*)d_in[6];
  const float* dec_cho = (const float*)d_in[7];
  float* out = (float*)d_out;

  float* ws = (float*)d_ws;
  float* lam0_ws = ws;              // 16384 floats
  float* eta0_ws = ws + 16384;      // 2048 floats

  k_scan<<<dim3(NSCAN), dim3(256), 0, stream>>>(sent, em_mu, em_cho, tr_mu,
                                                tr_cho, lam0_ws, eta0_ws);
  k_cons<<<dim3(1024), dim3(256), 0, stream>>>(lam0_ws, eta0_ws, dec_mu,
                                               dec_cho, out);
}

// Round 13
// 26.863 us; speedup vs baseline: 2.8837x; 1.1465x over previous
//
#include <hip/hip_runtime.h>
#include <math.h>

#define B_ 4
#define T_ 64
#define D_ 8
#define V_ 2000
#define LOG2PI_F 1.8378770664093453f
#define SEG 4                      /* steps per published segment */
#define NSEG (T_ / SEG)            /* 16 segments per batch */
#define WARM 8                     /* speculative warmup steps */
#define NSCAN (B_ * NSEG)          /* 64 scan blocks */

#define RCP(x) __builtin_amdgcn_rcpf(x)

__device__ __forceinline__ float rdl(float v, int lane) {
  return __int_as_float(__builtin_amdgcn_readlane(__float_as_int(v), lane));
}
// broadcast from lane k via the DS pipe (uniform bpermute address)
__device__ __forceinline__ float bpc(float v, int lane) {
  return __int_as_float(__builtin_amdgcn_ds_bpermute(lane * 4, __float_as_int(v)));
}

// Cholesky of (A + diag(dadd)) with A read from LDS (broadcast reads).
__device__ __forceinline__ float chol_quad_lds(const float* sA, const float dadd[D_],
                                               const float eta[D_], float& logdet) {
  float L[D_][D_];
  float rs[D_];
  float p0 = 1.f, p1 = 1.f;
#pragma unroll
  for (int j = 0; j < D_; ++j) {
    float c = sA[j * 8 + j] + dadd[j];
#pragma unroll
    for (int k = 0; k < D_; ++k) {
      if (k < j) c -= L[j][k] * L[j][k];
    }
    if (j < 4) p0 *= c; else p1 *= c;
    float r = rsqrtf(c);
    rs[j] = r;
#pragma unroll
    for (int i = 0; i < D_; ++i) {
      if (i > j) {
        float s = sA[i * 8 + j];
#pragma unroll
        for (int k = 0; k < D_; ++k) {
          if (k < j) s -= L[i][k] * L[j][k];
        }
        L[i][j] = s * r;
      }
    }
  }
  logdet = __logf(p0) + __logf(p1);
  float z[D_];
  float q = 0.f;
#pragma unroll
  for (int i = 0; i < D_; ++i) {
    float s = eta[i];
#pragma unroll
    for (int k = 0; k < D_; ++k) {
      if (k < i) s -= L[i][k] * z[k];
    }
    z[i] = s * rs[i];
    q = fmaf(z[i], z[i], q);
  }
  return q;
}

// Kernel 1: 64 scan blocks (b = bid>>4, s = bid&15), one chain per block.
// Segment s publishes t in [4s, 4s+4) after an (up to) 8-step warmup from the
// neutral init. Tail: 4 lanes compute zeta0 for the published steps.
extern "C" __global__ void __launch_bounds__(256)
k_scan(const int* __restrict__ sent, const float* __restrict__ em_mu,
       const float* __restrict__ em_cho, const float* __restrict__ tr_mu,
       const float* __restrict__ tr_cho, float* __restrict__ lam0_ws,
       float* __restrict__ eta0_ws, float* __restrict__ zeta0_ws) {
  const int bid = blockIdx.x;
  const int tid = threadIdx.x;

  __shared__ float sC[16][16], sCi[16][16], sLt[16][16];
  __shared__ float sEt[16], sMu[16];
  __shared__ float sLamW[16][8], sWmuT[16][8];
  __shared__ float sPubL[SEG][64], sPubE[SEG][8];
  const int b = bid >> 4;
  const int s = bid & (NSEG - 1);
  const int t_start = (s * SEG > WARM) ? (s * SEG - WARM) : 0;
  const int nsteps = s * SEG + SEG - t_start;   // 4, 8, or 12

  if (tid < nsteps) {
    const int swd = sent[b * T_ + t_start + tid];
    const float4* pc = (const float4*)(em_cho + swd * D_);
    const float4* pm = (const float4*)(em_mu + swd * D_);
    float4 c0 = pc[0], c1 = pc[1];
    float4 m0 = pm[0], m1 = pm[1];
    sLamW[tid][0] = RCP(c0.x * c0.x);
    sLamW[tid][1] = RCP(c0.y * c0.y);
    sLamW[tid][2] = RCP(c0.z * c0.z);
    sLamW[tid][3] = RCP(c0.w * c0.w);
    sLamW[tid][4] = RCP(c1.x * c1.x);
    sLamW[tid][5] = RCP(c1.y * c1.y);
    sLamW[tid][6] = RCP(c1.z * c1.z);
    sLamW[tid][7] = RCP(c1.w * c1.w);
    sWmuT[tid][0] = m0.x; sWmuT[tid][1] = m0.y;
    sWmuT[tid][2] = m0.z; sWmuT[tid][3] = m0.w;
    sWmuT[tid][4] = m1.x; sWmuT[tid][5] = m1.y;
    sWmuT[tid][6] = m1.z; sWmuT[tid][7] = m1.w;
  }

  // preamble: lam_t = inv(C^T C), eta_t = lam_t @ mu
  sC[tid >> 4][tid & 15] = tr_cho[tid];
  if (tid < 16) sMu[tid] = tr_mu[tid];
  __syncthreads();
  if (tid < 16) {
    const int j = tid;
    float col[16];
#pragma unroll
    for (int i = 0; i < 16; ++i) {
      float v = (i == j) ? 1.f : 0.f;
#pragma unroll
      for (int k = 0; k < 16; ++k) {
        if (k < i) v = fmaf(-sC[i][k], col[k], v);
      }
      col[i] = v * RCP(sC[i][i]);
    }
#pragma unroll
    for (int i = 0; i < 16; ++i) sCi[i][j] = col[i];
  }
  __syncthreads();
  {
    int i = tid >> 4, jq = tid & 15;
    float v = 0.f;
#pragma unroll
    for (int k = 0; k < 16; ++k) v = fmaf(sCi[i][k], sCi[jq][k], v);
    sLt[i][jq] = v;
  }
  __syncthreads();
  if (tid < 16) {
    float v = 0.f;
#pragma unroll
    for (int k = 0; k < 16; ++k) v = fmaf(sLt[tid][k], sMu[k], v);
    sEt[tid] = v;
  }
  __syncthreads();
  if (tid >= 64) return;  // wave 0 only from here; no more barriers

  const int i = tid & 7;
  float ltAA[8], ltAB[8], ltBA[8], ltBB[8];
#pragma unroll
  for (int j = 0; j < 8; ++j) {
    ltAA[j] = sLt[i][j];
    ltAB[j] = sLt[i][8 + j];
    ltBA[j] = sLt[8 + i][j];
    ltBB[j] = sLt[8 + i][8 + j];
  }
  const float etH = sEt[i], etT = sEt[8 + i];

  float lam[8];
#pragma unroll
  for (int j = 0; j < 8; ++j) lam[j] = (j == i) ? 1.f : 0.f;
  float eta = 0.f;

  float* lamOut = lam0_ws + b * T_ * 64;
  float* etaOut = eta0_ws + b * T_ * 8;

  float lamw = sLamW[0][i];
  float wmu = sWmuT[0][i];

#pragma unroll 1
  for (int tl = 0; tl < nsteps; ++tl) {
    float lamw_n = sLamW[(tl + 1) & 15][i];
    float wmu_n = sWmuT[(tl + 1) & 15][i];

    float A[8], Bm[8], Cr[8], Dm[8];
#pragma unroll
    for (int j = 0; j < 8; ++j) {
      A[j] = ltAA[j] + lam[j];
      Bm[j] = ltAB[j];
      Cr[j] = ltBA[j];
      Dm[j] = ltBB[j];
    }
    float ev = etH + eta;
    float et = etT;

    // 2x2-block forward elimination; k1-row via readlane (VALU pipe),
    // k2-row via ds_bpermute (DS pipe).
#pragma unroll
    for (int kk = 0; kk < 8; kk += 2) {
      const int k1 = kk, k2 = kk + 1;
      float sA1[8], sA2[8], sB1[8], sB2[8];
#pragma unroll
      for (int j = 0; j < 8; ++j) {
        if (j >= k1) {
          sA1[j] = rdl(A[j], k1);
          sA2[j] = bpc(A[j], k2);
        }
      }
#pragma unroll
      for (int j = 0; j < 8; ++j) {
        sB1[j] = rdl(Bm[j], k1);
        sB2[j] = bpc(Bm[j], k2);
      }
      float sE1 = rdl(ev, k1), sE2 = bpc(ev, k2);
      float p11 = sA1[k1], p12 = sA1[k2];
      float p21 = sA2[k1], p22 = sA2[k2];
      float rdet = RCP(fmaf(p11, p22, -(p12 * p21)));
      float a1 = A[k1], a2 = A[k2];
      float g1 = (i > k2) ? (a1 * p22 - a2 * p21) * rdet : 0.f;
      float g2 = (i > k2) ? (a2 * p11 - a1 * p12) * rdet : 0.f;
      float c1 = Cr[k1], c2 = Cr[k2];
      float h1 = (c1 * p22 - c2 * p21) * rdet;
      float h2 = (c2 * p11 - c1 * p12) * rdet;
#pragma unroll
      for (int j = 0; j < 8; ++j) {
        if (j >= kk + 2) {
          A[j] = fmaf(-g1, sA1[j], fmaf(-g2, sA2[j], A[j]));
          Cr[j] = fmaf(-h1, sA1[j], fmaf(-h2, sA2[j], Cr[j]));
        }
      }
#pragma unroll
      for (int j = 0; j < 8; ++j) {
        Bm[j] = fmaf(-g1, sB1[j], fmaf(-g2, sB2[j], Bm[j]));
        Dm[j] = fmaf(-h1, sB1[j], fmaf(-h2, sB2[j], Dm[j]));
      }
      ev = fmaf(-g1, sE1, fmaf(-g2, sE2, ev));
      et = fmaf(-h1, sE1, fmaf(-h2, sE2, et));
    }

    // epilogue: lam2 = Schur + diag(lamw); eta2 = et + lamw*wmu
#pragma unroll
    for (int j = 0; j < 8; ++j) lam[j] = (j == i) ? Dm[j] + lamw : Dm[j];
    eta = fmaf(lamw, wmu, et);

    const int t = t_start + tl;
    if (t >= s * SEG && tid < 8) {
      const int pi = t - s * SEG;
      float4* dst = (float4*)(lamOut + t * 64 + i * 8);
      dst[0] = make_float4(lam[0], lam[1], lam[2], lam[3]);
      dst[1] = make_float4(lam[4], lam[5], lam[6], lam[7]);
      etaOut[t * 8 + i] = eta;
#pragma unroll
      for (int j = 0; j < 8; ++j) sPubL[pi][i * 8 + j] = lam[j];
      sPubE[pi][i] = eta;
    }
    lamw = lamw_n;
    wmu = wmu_n;
  }

  // tail: lanes 0..3 compute zeta0 for the 4 published steps (one chol each)
  if (tid < SEG) {
    float e[D_], zero[D_];
#pragma unroll
    for (int j = 0; j < D_; ++j) {
      zero[j] = 0.f;
      e[j] = sPubE[tid][j];
    }
    float ld;
    float q = chol_quad_lds(&sPubL[tid][0], zero, e, ld);
    zeta0_ws[b * T_ + s * SEG + tid] = -0.5f * (8.f * LOG2PI_F - ld + q);
  }
}

// Kernel 2: 1024 consumer blocks; (bt = bid>>2, quarter = bid&3); each thread
// handles 2 cells, hand-inlined and independent (ILP on the chol chains).
extern "C" __global__ void __launch_bounds__(256)
k_cons(const float* __restrict__ lam0_ws, const float* __restrict__ eta0_ws,
       const float* __restrict__ zeta0_ws, const float* __restrict__ dec_mu,
       const float* __restrict__ dec_cho, float* __restrict__ out) {
  const int bt = blockIdx.x >> 2;
  const int quarter = blockIdx.x & 3;
  const int tid = threadIdx.x;

  __shared__ float sL[64];
  __shared__ float sE[8];
  if (tid < 64) sL[tid] = lam0_ws[bt * 64 + tid];
  if (tid < 8) sE[tid] = eta0_ws[bt * 8 + tid];
  __syncthreads();

  const float zeta0 = zeta0_ws[bt];
  float e0[D_];
#pragma unroll
  for (int ii = 0; ii < D_; ++ii) e0[ii] = sE[ii];

  // cell 0: off = tid in [0,256) < 500 -> always valid
  const int v0 = quarter * 500 + tid;
  // cell 1: off = 256+tid, valid iff < 500; clamp v for safe loads
  const bool has1 = (256 + tid) < 500;
  int v1 = quarter * 500 + 256 + tid;
  if (v1 > V_ - 1) v1 = V_ - 1;

  float dl0[D_], ef0[D_], dl1[D_], ef1[D_];
  float zeta1_0, zeta1_1;
  {
    const float4* pm = (const float4*)(dec_mu + v0 * D_);
    const float4* pc = (const float4*)(dec_cho + v0 * D_);
    float4 m0 = pm[0], m1 = pm[1];
    float4 c0 = pc[0], c1 = pc[1];
    float mv[D_] = {m0.x, m0.y, m0.z, m0.w, m1.x, m1.y, m1.z, m1.w};
    float cv[D_] = {c0.x, c0.y, c0.z, c0.w, c1.x, c1.y, c1.z, c1.w};
    float sl = 0.f, q1 = 0.f;
#pragma unroll
    for (int j = 0; j < D_; ++j) {
      float l = RCP(cv[j] * cv[j]);
      float e = mv[j] * l;
      dl0[j] = l;
      ef0[j] = e0[j] + e;
      sl += __logf(l);
      q1 = fmaf(e, mv[j], q1);
    }
    zeta1_0 = -0.5f * (8.f * LOG2PI_F - sl + q1);
  }
  {
    const float4* pm = (const float4*)(dec_mu + v1 * D_);
    const float4* pc = (const float4*)(dec_cho + v1 * D_);
    float4 m0 = pm[0], m1 = pm[1];
    float4 c0 = pc[0], c1 = pc[1];
    float mv[D_] = {m0.x, m0.y, m0.z, m0.w, m1.x, m1.y, m1.z, m1.w};
    float cv[D_] = {c0.x, c0.y, c0.z, c0.w, c1.x, c1.y, c1.z, c1.w};
    float sl = 0.f, q1 = 0.f;
#pragma unroll
    for (int j = 0; j < D_; ++j) {
      float l = RCP(cv[j] * cv[j]);
      float e = mv[j] * l;
      dl1[j] = l;
      ef1[j] = e0[j] + e;
      sl += __logf(l);
      q1 = fmaf(e, mv[j], q1);
    }
    zeta1_1 = -0.5f * (8.f * LOG2PI_F - sl + q1);
  }

  // two independent chol chains -> compiler interleaves (latency hiding)
  float ldn0, ldn1;
  float qn0 = chol_quad_lds(sL, dl0, ef0, ldn0);
  float qn1 = chol_quad_lds(sL, dl1, ef1, ldn1);
  const float zn0 = -0.5f * (8.f * LOG2PI_F - ldn0 + qn0);
  const float zn1 = -0.5f * (8.f * LOG2PI_F - ldn1 + qn1);

  out[bt * V_ + v0] = zeta0 + zeta1_0 - zn0;
  if (has1) out[bt * V_ + v1] = zeta0 + zeta1_1 - zn1;
}

extern "C" void kernel_launch(void* const* d_in, const int* in_sizes, int n_in,
                              void* d_out, int out_size, void* d_ws, size_t ws_size,
                              hipStream_t stream) {
  const int* sent = (const int*)d_in[0];
  const float* em_mu = (const float*)d_in[2];
  const float* em_cho = (const float*)d_in[3];
  const float* tr_mu = (const float*)d_in[4];
  const float* tr_cho = (const float*)d_in[5];
  const float* dec_mu = (const float*)d_in[6];
  const float* dec_cho = (const float*)d_in[7];
  float* out = (float*)d_out;

  float* ws = (float*)d_ws;
  float* lam0_ws = ws;               // 16384 floats
  float* eta0_ws = ws + 16384;       // 2048 floats
  float* zeta0_ws = ws + 16384 + 2048;  // 256 floats

  k_scan<<<dim3(NSCAN), dim3(256), 0, stream>>>(sent, em_mu, em_cho, tr_mu,
                                                tr_cho, lam0_ws, eta0_ws,
                                                zeta0_ws);
  k_cons<<<dim3(1024), dim3(256), 0, stream>>>(lam0_ws, eta0_ws, zeta0_ws,
                                               dec_mu, dec_cho, out);
}

// Round 14
// 20.780 us; speedup vs baseline: 3.7279x; 1.2928x over previous
//
#include <hip/hip_runtime.h>
#include <math.h>

#define B_ 4
#define T_ 64
#define D_ 8
#define V_ 2000
#define LOG2PI_F 1.8378770664093453f
#define CH 9   /* chain length: 8 warm steps + the target step (matches validated WARM=8) */

#define RCP(x) __builtin_amdgcn_rcpf(x)

__device__ __forceinline__ float rdl(float v, int lane) {
  return __int_as_float(__builtin_amdgcn_readlane(__float_as_int(v), lane));
}
// broadcast from lane k via the DS pipe (uniform bpermute address)
__device__ __forceinline__ float bpc(float v, int lane) {
  return __int_as_float(__builtin_amdgcn_ds_bpermute(lane * 4, __float_as_int(v)));
}

// Cholesky of (A + diag(dadd)) with A read from LDS (broadcast reads).
// Single grouped log for the determinant (range-safe: pivots in ~[1, 2e4],
// product of 8 <= ~2.5e34 < fp32 max).
__device__ __forceinline__ float chol_quad_lds(const float* sA, const float dadd[D_],
                                               const float eta[D_], float& logdet) {
  float L[D_][D_];
  float rs[D_];
  float p = 1.f;
#pragma unroll
  for (int j = 0; j < D_; ++j) {
    float c = sA[j * 8 + j] + dadd[j];
#pragma unroll
    for (int k = 0; k < D_; ++k) {
      if (k < j) c -= L[j][k] * L[j][k];
    }
    p *= c;
    float r = rsqrtf(c);
    rs[j] = r;
#pragma unroll
    for (int i = 0; i < D_; ++i) {
      if (i > j) {
        float s = sA[i * 8 + j];
#pragma unroll
        for (int k = 0; k < D_; ++k) {
          if (k < j) s -= L[i][k] * L[j][k];
        }
        L[i][j] = s * r;
      }
    }
  }
  logdet = __logf(p);
  float z[D_];
  float q = 0.f;
#pragma unroll
  for (int i = 0; i < D_; ++i) {
    float s = eta[i];
#pragma unroll
    for (int k = 0; k < D_; ++k) {
      if (k < i) s -= L[i][k] * z[k];
    }
    z[i] = s * rs[i];
    q = fmaf(z[i], z[i], q);
  }
  return q;
}

// ONE kernel, 256 blocks (one per (b,t)), 256 threads.
// Phase 1 (all threads): transition preamble + word staging.
// Phase 2 (wave 0): <=9-step information-filter chain for THIS t (8-step
//   speculative warmup from neutral init; exact for t<9). Result -> LDS.
// Phase 3 (all threads): 2000 vocab cells, 8 per thread, pair-interleaved.
extern "C" __global__ void __launch_bounds__(256)
k_all(const int* __restrict__ sent, const float* __restrict__ em_mu,
      const float* __restrict__ em_cho, const float* __restrict__ tr_mu,
      const float* __restrict__ tr_cho, const float* __restrict__ dec_mu,
      const float* __restrict__ dec_cho, float* __restrict__ out) {
  const int bt = blockIdx.x;
  const int tid = threadIdx.x;
  const int b = bt >> 6;
  const int t = bt & 63;
  const int t_start = (t >= CH) ? (t - CH + 1) : 0;
  const int nsteps = t - t_start + 1;  // 1..9

  __shared__ float sC[16][16], sCi[16][16], sLt[16][16];
  __shared__ float sEt[16], sMu[16];
  __shared__ float sLamW[16][8], sWmuT[16][8];
  __shared__ float sL[64], sE[8];

  // ---- stage this chain's word data ----
  if (tid < nsteps) {
    const int swd = sent[b * T_ + t_start + tid];
    const float4* pc = (const float4*)(em_cho + swd * D_);
    const float4* pm = (const float4*)(em_mu + swd * D_);
    float4 c0 = pc[0], c1 = pc[1];
    float4 m0 = pm[0], m1 = pm[1];
    sLamW[tid][0] = RCP(c0.x * c0.x);
    sLamW[tid][1] = RCP(c0.y * c0.y);
    sLamW[tid][2] = RCP(c0.z * c0.z);
    sLamW[tid][3] = RCP(c0.w * c0.w);
    sLamW[tid][4] = RCP(c1.x * c1.x);
    sLamW[tid][5] = RCP(c1.y * c1.y);
    sLamW[tid][6] = RCP(c1.z * c1.z);
    sLamW[tid][7] = RCP(c1.w * c1.w);
    sWmuT[tid][0] = m0.x; sWmuT[tid][1] = m0.y;
    sWmuT[tid][2] = m0.z; sWmuT[tid][3] = m0.w;
    sWmuT[tid][4] = m1.x; sWmuT[tid][5] = m1.y;
    sWmuT[tid][6] = m1.z; sWmuT[tid][7] = m1.w;
  }

  // ---- preamble: lam_t = inv(C^T C), eta_t = lam_t @ mu ----
  sC[tid >> 4][tid & 15] = tr_cho[tid];
  if (tid < 16) sMu[tid] = tr_mu[tid];
  __syncthreads();
  if (tid < 16) {
    const int j = tid;
    float col[16];
#pragma unroll
    for (int i = 0; i < 16; ++i) {
      float v = (i == j) ? 1.f : 0.f;
#pragma unroll
      for (int k = 0; k < 16; ++k) {
        if (k < i) v = fmaf(-sC[i][k], col[k], v);
      }
      col[i] = v * RCP(sC[i][i]);
    }
#pragma unroll
    for (int i = 0; i < 16; ++i) sCi[i][j] = col[i];
  }
  __syncthreads();
  {
    int i = tid >> 4, jq = tid & 15;
    float v = 0.f;
#pragma unroll
    for (int k = 0; k < 16; ++k) v = fmaf(sCi[i][k], sCi[jq][k], v);
    sLt[i][jq] = v;
  }
  __syncthreads();
  if (tid < 16) {
    float v = 0.f;
#pragma unroll
    for (int k = 0; k < 16; ++k) v = fmaf(sLt[tid][k], sMu[k], v);
    sEt[tid] = v;
  }
  __syncthreads();

  // ---- chain: wave 0 only (other waves park at the barrier below) ----
  if (tid < 64) {
    const int i = tid & 7;
    float ltAA[8], ltAB[8], ltBA[8], ltBB[8];
#pragma unroll
    for (int j = 0; j < 8; ++j) {
      ltAA[j] = sLt[i][j];
      ltAB[j] = sLt[i][8 + j];
      ltBA[j] = sLt[8 + i][j];
      ltBB[j] = sLt[8 + i][8 + j];
    }
    const float etH = sEt[i], etT = sEt[8 + i];

    float lam[8];
#pragma unroll
    for (int j = 0; j < 8; ++j) lam[j] = (j == i) ? 1.f : 0.f;
    float eta = 0.f;

    float lamw = sLamW[0][i];
    float wmu = sWmuT[0][i];

#pragma unroll 1
    for (int tl = 0; tl < nsteps; ++tl) {
      float lamw_n = sLamW[(tl + 1) & 15][i];
      float wmu_n = sWmuT[(tl + 1) & 15][i];

      float A[8], Bm[8], Cr[8], Dm[8];
#pragma unroll
      for (int j = 0; j < 8; ++j) {
        A[j] = ltAA[j] + lam[j];
        Bm[j] = ltAB[j];
        Cr[j] = ltBA[j];
        Dm[j] = ltBB[j];
      }
      float ev = etH + eta;
      float et = etT;

      // 2x2-block forward elimination; k1-row via readlane (VALU pipe),
      // k2-row via ds_bpermute (DS pipe).
#pragma unroll
      for (int kk = 0; kk < 8; kk += 2) {
        const int k1 = kk, k2 = kk + 1;
        float sA1[8], sA2[8], sB1[8], sB2[8];
#pragma unroll
        for (int j = 0; j < 8; ++j) {
          if (j >= k1) {
            sA1[j] = rdl(A[j], k1);
            sA2[j] = bpc(A[j], k2);
          }
        }
#pragma unroll
        for (int j = 0; j < 8; ++j) {
          sB1[j] = rdl(Bm[j], k1);
          sB2[j] = bpc(Bm[j], k2);
        }
        float sE1 = rdl(ev, k1), sE2 = bpc(ev, k2);
        float p11 = sA1[k1], p12 = sA1[k2];
        float p21 = sA2[k1], p22 = sA2[k2];
        float rdet = RCP(fmaf(p11, p22, -(p12 * p21)));
        float a1 = A[k1], a2 = A[k2];
        float g1 = (i > k2) ? (a1 * p22 - a2 * p21) * rdet : 0.f;
        float g2 = (i > k2) ? (a2 * p11 - a1 * p12) * rdet : 0.f;
        float c1 = Cr[k1], c2 = Cr[k2];
        float h1 = (c1 * p22 - c2 * p21) * rdet;
        float h2 = (c2 * p11 - c1 * p12) * rdet;
#pragma unroll
        for (int j = 0; j < 8; ++j) {
          if (j >= kk + 2) {
            A[j] = fmaf(-g1, sA1[j], fmaf(-g2, sA2[j], A[j]));
            Cr[j] = fmaf(-h1, sA1[j], fmaf(-h2, sA2[j], Cr[j]));
          }
        }
#pragma unroll
        for (int j = 0; j < 8; ++j) {
          Bm[j] = fmaf(-g1, sB1[j], fmaf(-g2, sB2[j], Bm[j]));
          Dm[j] = fmaf(-h1, sB1[j], fmaf(-h2, sB2[j], Dm[j]));
        }
        ev = fmaf(-g1, sE1, fmaf(-g2, sE2, ev));
        et = fmaf(-h1, sE1, fmaf(-h2, sE2, et));
      }

      // epilogue: lam2 = Schur + diag(lamw); eta2 = et + lamw*wmu
#pragma unroll
      for (int j = 0; j < 8; ++j) lam[j] = (j == i) ? Dm[j] + lamw : Dm[j];
      eta = fmaf(lamw, wmu, et);
      lamw = lamw_n;
      wmu = wmu_n;
    }

    if (tid < 8) {
#pragma unroll
      for (int j = 0; j < 8; ++j) sL[i * 8 + j] = lam[j];
      sE[i] = eta;
    }
  }
  __syncthreads();

  // ---- cell phase: all 256 threads ----
  float e0[D_], zero[D_];
#pragma unroll
  for (int j = 0; j < D_; ++j) {
    e0[j] = sE[j];
    zero[j] = 0.f;
  }
  float ld0;
  float q0 = chol_quad_lds(sL, zero, e0, ld0);
  const float zeta0 = -0.5f * (8.f * LOG2PI_F - ld0 + q0);

  float* outRow = out + bt * V_;

#pragma unroll 1
  for (int it = 0; it < 4; ++it) {
    const int off = it * 256 + tid;
    if (off < 1000) {
      const int v0 = off, v1 = off + 1000;
      float dl0[D_], ef0[D_], dl1[D_], ef1[D_];
      float zeta1_0, zeta1_1;
      {
        const float4* pm = (const float4*)(dec_mu + v0 * D_);
        const float4* pc = (const float4*)(dec_cho + v0 * D_);
        float4 m0 = pm[0], m1 = pm[1];
        float4 c0 = pc[0], c1 = pc[1];
        float mv[D_] = {m0.x, m0.y, m0.z, m0.w, m1.x, m1.y, m1.z, m1.w};
        float cv[D_] = {c0.x, c0.y, c0.z, c0.w, c1.x, c1.y, c1.z, c1.w};
        float pr = 1.f, q1 = 0.f;
#pragma unroll
        for (int j = 0; j < D_; ++j) {
          float l = RCP(cv[j] * cv[j]);
          float e = mv[j] * l;
          dl0[j] = l;
          ef0[j] = e0[j] + e;
          pr *= fabsf(cv[j]);
          q1 = fmaf(e, mv[j], q1);
        }
        zeta1_0 = -0.5f * (8.f * LOG2PI_F + 2.f * __logf(pr) + q1);
      }
      {
        const float4* pm = (const float4*)(dec_mu + v1 * D_);
        const float4* pc = (const float4*)(dec_cho + v1 * D_);
        float4 m0 = pm[0], m1 = pm[1];
        float4 c0 = pc[0], c1 = pc[1];
        float mv[D_] = {m0.x, m0.y, m0.z, m0.w, m1.x, m1.y, m1.z, m1.w};
        float cv[D_] = {c0.x, c0.y, c0.z, c0.w, c1.x, c1.y, c1.z, c1.w};
        float pr = 1.f, q1 = 0.f;
#pragma unroll
        for (int j = 0; j < D_; ++j) {
          float l = RCP(cv[j] * cv[j]);
          float e = mv[j] * l;
          dl1[j] = l;
          ef1[j] = e0[j] + e;
          pr *= fabsf(cv[j]);
          q1 = fmaf(e, mv[j], q1);
        }
        zeta1_1 = -0.5f * (8.f * LOG2PI_F + 2.f * __logf(pr) + q1);
      }

      // two independent chol chains -> compiler interleaves (latency hiding)
      float ldn0, ldn1;
      float qn0 = chol_quad_lds(sL, dl0, ef0, ldn0);
      float qn1 = chol_quad_lds(sL, dl1, ef1, ldn1);
      const float zn0 = -0.5f * (8.f * LOG2PI_F - ldn0 + qn0);
      const float zn1 = -0.5f * (8.f * LOG2PI_F - ldn1 + qn1);

      outRow[v0] = zeta0 + zeta1_0 - zn0;
      outRow[v1] = zeta0 + zeta1_1 - zn1;
    }
  }
}

extern "C" void kernel_launch(void* const* d_in, const int* in_sizes, int n_in,
                              void* d_out, int out_size, void* d_ws, size_t ws_size,
                              hipStream_t stream) {
  const int* sent = (const int*)d_in[0];
  const float* em_mu = (const float*)d_in[2];
  const float* em_cho = (const float*)d_in[3];
  const float* tr_mu = (const float*)d_in[4];
  const float* tr_cho = (const float*)d_in[5];
  const float* dec_mu = (const float*)d_in[6];
  const float* dec_cho = (const float*)d_in[7];
  float* out = (float*)d_out;

  k_all<<<dim3(B_ * T_), dim3(256), 0, stream>>>(sent, em_mu, em_cho, tr_mu,
                                                 tr_cho, dec_mu, dec_cho, out);
}